// Round 8
// baseline (504.058 us; speedup 1.0000x reference)
//
#include <hip/hip_runtime.h>
#include <hip/hip_bf16.h>
#include <stdint.h>

// MultiheadAttention (GPT-2 style), B=2 S=2048 NX=1024 H=16 D=64.
// fp32 in / fp32 out, bf16 MFMA internals.
// R8: attn rebuilt barrier-free — K/V read direct from global (L2-resident,
// Common-mistake #7), no LDS staging, waves independent. GEMMs unchanged.

typedef __bf16 bf16;
typedef __attribute__((ext_vector_type(8))) __bf16 bf16x8;
typedef __attribute__((ext_vector_type(4))) float f32x4;

#define SEQ 2048
#define NXD 1024
#define DH 64
#define LP 72  // padded LDS row stride (elems)

__device__ __forceinline__ f32x4 mfma16(bf16x8 a, bf16x8 b, f32x4 c) {
  return __builtin_amdgcn_mfma_f32_16x16x32_bf16(a, b, c, 0, 0, 0);
}

// ---------------- fp32 -> bf16 elementwise (8 elems/thread) ----------------
__global__ __launch_bounds__(256) void convert_f32_bf16(
    const float* __restrict__ in, bf16* __restrict__ out, int n8) {
  const int i = blockIdx.x * 256 + threadIdx.x;
  if (i >= n8) return;
  const float4 a = ((const float4*)in)[i * 2];
  const float4 b = ((const float4*)in)[i * 2 + 1];
  bf16x8 o;
  o[0] = (bf16)a.x; o[1] = (bf16)a.y; o[2] = (bf16)a.z; o[3] = (bf16)a.w;
  o[4] = (bf16)b.x; o[5] = (bf16)b.y; o[6] = (bf16)b.z; o[7] = (bf16)b.w;
  ((bf16x8*)out)[i] = o;
}

// -- fp32 [z][R][C] -> bf16 transposed [z][C][R], 64x64 tiles, batched ------
__global__ __launch_bounds__(256) void transpose64_f2b(
    const float* __restrict__ in, bf16* __restrict__ out, int R, int C) {
  __shared__ bf16 tile[64 * 65];
  const int t = threadIdx.x;
  const size_t bofs = (size_t)blockIdx.z * R * C;
  const float* ib = in + bofs;
  bf16* ob = out + bofs;
  const int r0 = blockIdx.y * 64, c0 = blockIdx.x * 64;
#pragma unroll
  for (int i = 0; i < 4; i++) {
    int flat = (i * 256 + t) * 4;
    int row = flat >> 6, col = flat & 63;
    float4 v = *(const float4*)(ib + (size_t)(r0 + row) * C + c0 + col);
    tile[row * 65 + col + 0] = (bf16)v.x;
    tile[row * 65 + col + 1] = (bf16)v.y;
    tile[row * 65 + col + 2] = (bf16)v.z;
    tile[row * 65 + col + 3] = (bf16)v.w;
  }
  __syncthreads();
#pragma unroll
  for (int i = 0; i < 2; i++) {
    int flat = (i * 256 + t) * 8;
    int orow = flat >> 6, ocol = flat & 63;
    bf16x8 v;
#pragma unroll
    for (int e = 0; e < 8; e++) v[e] = tile[(ocol + e) * 65 + orow];
    *(bf16x8*)(ob + (size_t)(c0 + orow) * R + r0 + ocol) = v;
  }
}

// ---------------- 128x128 bf16 GEMM, K=1024, A:[M][1024], BT:[N][1024] -----
// MODE 0: qkv scatter: q -> qb (bf16 [B,H,S,D]), k -> of1, v -> of2 (fp32)
// MODE 1: plain fp32 out [M][1024] -> of1.
template <int MODE>
__global__ __launch_bounds__(256) void gemm128s(
    const bf16* __restrict__ A, const bf16* __restrict__ BT,
    const float* __restrict__ bias, bf16* __restrict__ qb,
    float* __restrict__ of1, float* __restrict__ of2) {
  __shared__ bf16 As[128 * LP];
  __shared__ bf16 Bs[128 * LP];
  const int t = threadIdx.x;
  const int lane = t & 63, wave = t >> 6;
  const int hi = lane >> 4, ln = lane & 15;
  const int wr = wave >> 1, wc = wave & 1;
  const int tm0 = blockIdx.y * 128, tn0 = blockIdx.x * 128;

  f32x4 acc[4][4];
#pragma unroll
  for (int m = 0; m < 4; m++)
#pragma unroll
    for (int n = 0; n < 4; n++) acc[m][n] = (f32x4){0.f, 0.f, 0.f, 0.f};

  for (int k0 = 0; k0 < 1024; k0 += 64) {
#pragma unroll
    for (int it = 0; it < 4; ++it) {
      const int e = (it * 256 + t) * 8;
      const int row = e >> 6, col = e & 63;
      *(bf16x8*)(As + row * LP + col) =
          *(const bf16x8*)(A + (size_t)(tm0 + row) * 1024 + k0 + col);
      *(bf16x8*)(Bs + row * LP + col) =
          *(const bf16x8*)(BT + (size_t)(tn0 + row) * 1024 + k0 + col);
    }
    __syncthreads();
#pragma unroll
    for (int kk = 0; kk < 2; ++kk) {
      bf16x8 af[4], bfr[4];
#pragma unroll
      for (int m = 0; m < 4; m++) {
        const int ar = wr * 64 + m * 16 + ln;
        af[m] = *(const bf16x8*)(As + ar * LP + kk * 32 + hi * 8);
      }
#pragma unroll
      for (int n = 0; n < 4; n++) {
        const int br = wc * 64 + n * 16 + ln;
        bfr[n] = *(const bf16x8*)(Bs + br * LP + kk * 32 + hi * 8);
      }
#pragma unroll
      for (int m = 0; m < 4; m++)
#pragma unroll
        for (int n = 0; n < 4; n++)
          acc[m][n] = mfma16(af[m], bfr[n], acc[m][n]);
    }
    __syncthreads();
  }
#pragma unroll
  for (int m = 0; m < 4; m++) {
#pragma unroll
    for (int n = 0; n < 4; n++) {
      const int c = tn0 + wc * 64 + n * 16 + ln;
      const float bv = bias[c];
#pragma unroll
      for (int reg = 0; reg < 4; reg++) {
        const int r = tm0 + wr * 64 + m * 16 + hi * 4 + reg;
        const float v = acc[m][n][reg] + bv;
        if (MODE == 0) {
          const int b = r >> 11, s = r & 2047;
          const int which = c >> 10, cc = c & 1023;
          const int h = cc >> 6, dc = cc & 63;
          const size_t idx = (((size_t)(b * 16 + h)) * 2048 + s) * 64 + dc;
          if (which == 0) qb[idx] = (bf16)v;       // q: bf16 ws
          else if (which == 1) of1[idx] = v;       // k: fp32 present
          else of2[idx] = v;                       // v: fp32 present
        } else {
          of1[(size_t)r * 1024 + c] = v;           // fp32 out
        }
      }
    }
  }
}

// ---------------- causal flash attention, barrier-free ----------------
// Q bf16 ws [B,H,S,D]; K fp32 present [B,H,S,D] (cvt on the fly);
// VT bf16 ws [B,H,D,S]; Aout bf16 ws [B,S,NX].
// grid (S/64, B*H); 4 independent waves x 16 q-rows; no __syncthreads.
__global__ __launch_bounds__(256) void attn_kernel(
    const bf16* __restrict__ Q, const float* __restrict__ K,
    const bf16* __restrict__ VT, bf16* __restrict__ Aout) {
  __shared__ bf16 Pall[4 * 16 * LP];  // wave-private P buffers only
  const int t = threadIdx.x, lane = t & 63, wave = t >> 6;
  const int hi = lane >> 4, ln = lane & 15;
  bf16* Psw = Pall + wave * 16 * LP;
  const int qt = blockIdx.x, bh = blockIdx.y;
  const int qrow_base = qt * 64 + wave * 16;

  bf16x8 qf[2];
#pragma unroll
  for (int kk = 0; kk < 2; kk++)
    qf[kk] = *(const bf16x8*)(Q + ((size_t)bh * SEQ + qrow_base + ln) * DH +
                              kk * 32 + hi * 8);

  const float* Kb = K + (size_t)bh * SEQ * DH;
  const bf16* VTb = VT + (size_t)bh * DH * SEQ;

  f32x4 o[4];
#pragma unroll
  for (int nd = 0; nd < 4; nd++) o[nd] = (f32x4){0.f, 0.f, 0.f, 0.f};
  float mrun[4], lrun[4];
#pragma unroll
  for (int r = 0; r < 4; r++) { mrun[r] = -3e38f; lrun[r] = 0.f; }

  for (int j = 0; j <= qt; ++j) {
    // scores S = Q K^T ; K read direct from global fp32, cvt in regs
    f32x4 s[4];
#pragma unroll
    for (int n = 0; n < 4; n++) s[n] = (f32x4){0.f, 0.f, 0.f, 0.f};
#pragma unroll
    for (int kk = 0; kk < 2; kk++) {
#pragma unroll
      for (int n = 0; n < 4; n++) {
        const float* kp =
            Kb + (size_t)(j * 64 + n * 16 + ln) * DH + kk * 32 + hi * 8;
        const float4 f0 = *(const float4*)kp;
        const float4 f1 = *(const float4*)(kp + 4);
        bf16x8 kf;
        kf[0] = (bf16)f0.x; kf[1] = (bf16)f0.y;
        kf[2] = (bf16)f0.z; kf[3] = (bf16)f0.w;
        kf[4] = (bf16)f1.x; kf[5] = (bf16)f1.y;
        kf[6] = (bf16)f1.z; kf[7] = (bf16)f1.w;
        s[n] = mfma16(qf[kk], kf, s[n]);
      }
    }
    const bool diag = (j == qt);
#pragma unroll
    for (int n = 0; n < 4; n++) {
#pragma unroll
      for (int reg = 0; reg < 4; reg++) {
        float v = s[n][reg] * (1.f / 64.f);  // module scales by 1/d (not sqrt)
        if (diag) {
          const int col = j * 64 + n * 16 + ln;
          const int row = qrow_base + hi * 4 + reg;
          if (col > row) v = -1e10f;
        }
        s[n][reg] = v;
      }
    }
    // online softmax: row = 16 lanes sharing `hi`, 4 cols each
    float pm[4];
#pragma unroll
    for (int reg = 0; reg < 4; reg++)
      pm[reg] = fmaxf(fmaxf(s[0][reg], s[1][reg]), fmaxf(s[2][reg], s[3][reg]));
#pragma unroll
    for (int off = 1; off < 16; off <<= 1)
#pragma unroll
      for (int reg = 0; reg < 4; reg++)
        pm[reg] = fmaxf(pm[reg], __shfl_xor(pm[reg], off));
    float alpha[4];
#pragma unroll
    for (int reg = 0; reg < 4; reg++) {
      const float mnew = fmaxf(mrun[reg], pm[reg]);
      alpha[reg] = __expf(mrun[reg] - mnew);
      mrun[reg] = mnew;
    }
    float rs[4] = {0.f, 0.f, 0.f, 0.f};
#pragma unroll
    for (int n = 0; n < 4; n++)
#pragma unroll
      for (int reg = 0; reg < 4; reg++) {
        const float p = __expf(s[n][reg] - mrun[reg]);
        s[n][reg] = p;
        rs[reg] += p;
      }
#pragma unroll
    for (int off = 1; off < 16; off <<= 1)
#pragma unroll
      for (int reg = 0; reg < 4; reg++) rs[reg] += __shfl_xor(rs[reg], off);
#pragma unroll
    for (int reg = 0; reg < 4; reg++)
      lrun[reg] = lrun[reg] * alpha[reg] + rs[reg];
#pragma unroll
    for (int nd = 0; nd < 4; nd++)
#pragma unroll
      for (int reg = 0; reg < 4; reg++) o[nd][reg] *= alpha[reg];
    // P -> wave-private padded LDS (same-wave roundtrip, no barrier)
#pragma unroll
    for (int n = 0; n < 4; n++)
#pragma unroll
      for (int reg = 0; reg < 4; reg++)
        Psw[(hi * 4 + reg) * LP + n * 16 + ln] = (bf16)s[n][reg];
    // PV: V^T read direct from global bf16
#pragma unroll
    for (int kk = 0; kk < 2; kk++) {
      bf16x8 pa = *(const bf16x8*)(Psw + ln * LP + kk * 32 + hi * 8);
#pragma unroll
      for (int nd = 0; nd < 4; nd++) {
        bf16x8 vf = *(const bf16x8*)(VTb + (size_t)(nd * 16 + ln) * SEQ +
                                     j * 64 + kk * 32 + hi * 8);
        o[nd] = mfma16(pa, vf, o[nd]);
      }
    }
  }
  // write merged-heads a (bf16): [B,S,NX]
  const int bq = bh >> 4, h = bh & 15;
#pragma unroll
  for (int nd = 0; nd < 4; nd++)
#pragma unroll
    for (int reg = 0; reg < 4; reg++) {
      const int srow = qrow_base + hi * 4 + reg;
      const float inv = 1.f / lrun[reg];
      Aout[((size_t)bq * SEQ + srow) * NXD + h * 64 + nd * 16 + ln] =
          (bf16)(o[nd][reg] * inv);
    }
}

extern "C" void kernel_launch(void* const* d_in, const int* in_sizes, int n_in,
                              void* d_out, int out_size, void* d_ws,
                              size_t ws_size, hipStream_t stream) {
  const float* x = (const float*)d_in[0];        // [B,S,NX] fp32
  const float* w_attn = (const float*)d_in[1];   // [1024,3072] fp32
  const float* b_attn = (const float*)d_in[2];   // [3072] fp32
  const float* w_proj = (const float*)d_in[3];   // [1024,1024] fp32
  const float* b_proj = (const float*)d_in[4];   // [1024] fp32

  float* out = (float*)d_out;            // [B,S,NX] fp32
  float* kout = out + 4194304;           // present[0] [B,H,S,D] fp32
  float* vout = kout + 4194304;          // present[1] [B,H,S,D] fp32

  bf16* wT = (bf16*)d_ws;                // [3072][1024] bf16   6.29MB
  bf16* wpT = wT + 3072 * 1024;          // [1024][1024] bf16   2.10MB
  bf16* Qws = wpT + 1024 * 1024;         // [B,H,S,D]    bf16   8.39MB
  bf16* VTws = Qws + 4194304;            // [B,H,D,S]    bf16   8.39MB
  bf16* Aws = VTws + 4194304;            // [B,S,NX]     bf16   8.39MB (33.6MB)
  bf16* Xb = Aws;  // x-as-bf16 parks here until gemm<0> consumes it

  convert_f32_bf16<<<dim3(2048), 256, 0, stream>>>(x, Xb, 524288);
  transpose64_f2b<<<dim3(48, 16, 1), 256, 0, stream>>>(w_attn, wT, 1024, 3072);
  transpose64_f2b<<<dim3(16, 16, 1), 256, 0, stream>>>(w_proj, wpT, 1024,
                                                       1024);
  gemm128s<0><<<dim3(24, 32), 256, 0, stream>>>(Xb, wT, b_attn, Qws, kout,
                                                vout);
  // V^T per head: fp32 [S][D] -> bf16 [D][S], batched over B*H=32
  transpose64_f2b<<<dim3(1, 32, 32), 256, 0, stream>>>(vout, VTws, 2048, 64);
  attn_kernel<<<dim3(32, 32), 256, 0, stream>>>(Qws, kout, VTws, Aws);
  gemm128s<1><<<dim3(8, 32), 256, 0, stream>>>(Aws, wpT, b_proj, nullptr, out,
                                               nullptr);
}

// Round 12
// 238.497 us; speedup vs baseline: 2.1135x; 2.1135x over previous
//
#include <hip/hip_runtime.h>
#include <hip/hip_bf16.h>
#include <stdint.h>

// MultiheadAttention (GPT-2 style), B=2 S=2048 NX=1024 H=16 D=64.
// fp32 in / fp32 out, bf16 MFMA internals.
// R9: attn = staged LDS again but double-buffered, 1 barrier/tile, async
// reg-stage (T14), causal pair load-balancing. GEMMs = m97 structure
// (global_load_lds w16 + XOR swizzle, HW-exercised in R3).

typedef __bf16 bf16;
typedef __attribute__((ext_vector_type(8))) __bf16 bf16x8;
typedef __attribute__((ext_vector_type(4))) float f32x4;

#define SEQ 2048
#define NXD 1024
#define DH 64
#define LP 72  // padded LDS row stride (elems) for attn tiles
#define NT 32  // number of 64-row q tiles

__device__ __forceinline__ void gload16(const void* g, void* l) {
  __builtin_amdgcn_global_load_lds(
      (const __attribute__((address_space(1))) uint32_t*)(uintptr_t)g,
      (__attribute__((address_space(3))) uint32_t*)(uintptr_t)l, 16, 0, 0);
}

__device__ __forceinline__ f32x4 mfma16(bf16x8 a, bf16x8 b, f32x4 c) {
  return __builtin_amdgcn_mfma_f32_16x16x32_bf16(a, b, c, 0, 0, 0);
}

// ---------------- fp32 -> bf16 elementwise (8 elems/thread) ----------------
__global__ __launch_bounds__(256) void convert_f32_bf16(
    const float* __restrict__ in, bf16* __restrict__ out, int n8) {
  const int i = blockIdx.x * 256 + threadIdx.x;
  if (i >= n8) return;
  const float4 a = ((const float4*)in)[i * 2];
  const float4 b = ((const float4*)in)[i * 2 + 1];
  bf16x8 o;
  o[0] = (bf16)a.x; o[1] = (bf16)a.y; o[2] = (bf16)a.z; o[3] = (bf16)a.w;
  o[4] = (bf16)b.x; o[5] = (bf16)b.y; o[6] = (bf16)b.z; o[7] = (bf16)b.w;
  ((bf16x8*)out)[i] = o;
}

// -- fp32 [z][R][C] -> bf16 transposed [z][C][R], 64x64 tiles, batched ------
__global__ __launch_bounds__(256) void transpose64_f2b(
    const float* __restrict__ in, bf16* __restrict__ out, int R, int C) {
  __shared__ bf16 tile[64 * 65];
  const int t = threadIdx.x;
  const size_t bofs = (size_t)blockIdx.z * R * C;
  const float* ib = in + bofs;
  bf16* ob = out + bofs;
  const int r0 = blockIdx.y * 64, c0 = blockIdx.x * 64;
#pragma unroll
  for (int i = 0; i < 4; i++) {
    int flat = (i * 256 + t) * 4;
    int row = flat >> 6, col = flat & 63;
    float4 v = *(const float4*)(ib + (size_t)(r0 + row) * C + c0 + col);
    tile[row * 65 + col + 0] = (bf16)v.x;
    tile[row * 65 + col + 1] = (bf16)v.y;
    tile[row * 65 + col + 2] = (bf16)v.z;
    tile[row * 65 + col + 3] = (bf16)v.w;
  }
  __syncthreads();
#pragma unroll
  for (int i = 0; i < 2; i++) {
    int flat = (i * 256 + t) * 8;
    int orow = flat >> 6, ocol = flat & 63;
    bf16x8 v;
#pragma unroll
    for (int e = 0; e < 8; e++) v[e] = tile[(ocol + e) * 65 + orow];
    *(bf16x8*)(ob + (size_t)(c0 + orow) * R + r0 + ocol) = v;
  }
}

// ------- 128x128 bf16 GEMM (m97 structure), K=1024, A:[M][1024] ------------
// BT:[N][1024]. Staging: global_load_lds w16, linear LDS dest, inverse-
// swizzled global src; reads swizzled (rule #21 pair, HW-exercised in R3).
// MODE 0: qkv scatter: q->qb (bf16 [B,H,S,D]), k->of1, v->of2 (fp32 present)
// MODE 1: plain fp32 out [M][1024] -> of1
template <int MODE>
__global__ __launch_bounds__(256) void gemm128(
    const bf16* __restrict__ A, const bf16* __restrict__ BT,
    const float* __restrict__ bias, bf16* __restrict__ qb,
    float* __restrict__ of1, float* __restrict__ of2) {
  __shared__ char smem[32768];  // As 16KB | Bs 16KB
  bf16* As = (bf16*)smem;
  bf16* Bs = (bf16*)(smem + 16384);
  const int t = threadIdx.x;
  const int lane = t & 63, wave = t >> 6;
  const int hi = lane >> 4, ln = lane & 15;
  const int wr = wave >> 1, wc = wave & 1;
  const int tm0 = blockIdx.y * 128, tn0 = blockIdx.x * 128;

  f32x4 acc[4][4];
#pragma unroll
  for (int m = 0; m < 4; m++)
#pragma unroll
    for (int n = 0; n < 4; n++) acc[m][n] = (f32x4){0.f, 0.f, 0.f, 0.f};

  for (int k0 = 0; k0 < 1024; k0 += 64) {
#pragma unroll
    for (int cch = 0; cch < 4; ++cch) {
      const int fb = cch * 4096 + wave * 1024;  // wave-uniform byte base
      const int f = fb + lane * 16;
      const int row = f >> 7;                     // 128B per row
      const int sc = ((f >> 4) & 7) ^ (row & 7);  // 16B-unit swizzle
      gload16(A + (size_t)(tm0 + row) * 1024 + k0 + sc * 8, smem + fb);
      gload16(BT + (size_t)(tn0 + row) * 1024 + k0 + sc * 8,
              smem + 16384 + fb);
    }
    __syncthreads();
#pragma unroll
    for (int kk = 0; kk < 2; ++kk) {
      bf16x8 af[4], bfr[4];
#pragma unroll
      for (int m = 0; m < 4; m++) {
        const int ar = wr * 64 + m * 16 + ln;
        af[m] = *(const bf16x8*)(As + ar * 64 +
                                 ((kk * 32 + hi * 8) ^ ((ar & 7) << 3)));
      }
#pragma unroll
      for (int n = 0; n < 4; n++) {
        const int br = wc * 64 + n * 16 + ln;
        bfr[n] = *(const bf16x8*)(Bs + br * 64 +
                                  ((kk * 32 + hi * 8) ^ ((br & 7) << 3)));
      }
#pragma unroll
      for (int m = 0; m < 4; m++)
#pragma unroll
        for (int n = 0; n < 4; n++)
          acc[m][n] = mfma16(af[m], bfr[n], acc[m][n]);
    }
    __syncthreads();
  }
  // epilogue: C/D layout col=lane&15, row=(lane>>4)*4+reg
#pragma unroll
  for (int m = 0; m < 4; m++) {
#pragma unroll
    for (int n = 0; n < 4; n++) {
      const int c = tn0 + wc * 64 + n * 16 + ln;
      const float bv = bias[c];
#pragma unroll
      for (int reg = 0; reg < 4; reg++) {
        const int r = tm0 + wr * 64 + m * 16 + hi * 4 + reg;
        const float v = acc[m][n][reg] + bv;
        if (MODE == 0) {
          const int b = r >> 11, s = r & 2047;
          const int which = c >> 10, cc = c & 1023;
          const int h = cc >> 6, dc = cc & 63;
          const size_t idx = (((size_t)(b * 16 + h)) * 2048 + s) * 64 + dc;
          if (which == 0) qb[idx] = (bf16)v;       // q: bf16 ws
          else if (which == 1) of1[idx] = v;       // k: fp32 present
          else of2[idx] = v;                       // v: fp32 present
        } else {
          of1[(size_t)r * 1024 + c] = v;           // fp32 out
        }
      }
    }
  }
}

// ---------------- causal flash attention, dbuf + paired tiles --------------
// Q bf16 ws [B,H,S,D]; K fp32 present [B,H,S,D] (cvt during stage);
// VT bf16 ws [B,H,D,S]; Aout bf16 ws [B,S,NX].
// grid (NT/2, B*H); block bid handles q-tiles {bid, NT-1-bid} (uniform 33
// KV-tiles). 4 waves x 16 q-rows. Double-buffered K/V LDS, 1 barrier/tile,
// T14 async reg-stage (loads for j+1 issued before compute of j).
__global__ __launch_bounds__(256) void attn_kernel(
    const bf16* __restrict__ Q, const float* __restrict__ K,
    const bf16* __restrict__ VT, bf16* __restrict__ Aout) {
  __shared__ bf16 KsBuf[2][64 * LP];
  __shared__ bf16 VsBuf[2][64 * LP];
  __shared__ bf16 Pall[4 * 16 * LP];
  const int t = threadIdx.x, lane = t & 63, wave = t >> 6;
  const int hi = lane >> 4, ln = lane & 15;
  bf16* Psw = Pall + wave * 16 * LP;
  const int bid = blockIdx.x, bh = blockIdx.y;
  const int bq = bh >> 4, h = bh & 15;

  const float* Kb = K + (size_t)bh * SEQ * DH;
  const bf16* VTb = VT + (size_t)bh * DH * SEQ;

  // stage regs: each thread owns rows {t/8, 32+t/8}, col 8*(t%8)
  const int srow0 = t >> 3, scol = (t & 7) * 8;
  float4 kreg[2][2];
  bf16x8 vreg[2];

#pragma unroll
  for (int half = 0; half < 2; ++half) {
    const int qt = half ? (NT - 1 - bid) : bid;
    const int qrow_base = qt * 64 + wave * 16;

    bf16x8 qf[2];
#pragma unroll
    for (int kk = 0; kk < 2; kk++)
      qf[kk] = *(const bf16x8*)(Q + ((size_t)bh * SEQ + qrow_base + ln) * DH +
                                kk * 32 + hi * 8);

    f32x4 o[4];
#pragma unroll
    for (int nd = 0; nd < 4; nd++) o[nd] = (f32x4){0.f, 0.f, 0.f, 0.f};
    float mrun[4], lrun[4];
#pragma unroll
    for (int r = 0; r < 4; r++) { mrun[r] = -3e38f; lrun[r] = 0.f; }

    // prologue: load tile 0 into regs
#pragma unroll
    for (int it = 0; it < 2; ++it) {
      const int row = srow0 + it * 32;
      const float* kp = Kb + (size_t)row * DH + scol;
      kreg[it][0] = *(const float4*)kp;
      kreg[it][1] = *(const float4*)(kp + 4);
      vreg[it] = *(const bf16x8*)(VTb + (size_t)row * SEQ + scol);
    }

    for (int j = 0; j <= qt; ++j) {
      bf16* Ks = KsBuf[j & 1];
      bf16* Vs = VsBuf[j & 1];
      // write staged regs -> LDS buf[j&1]
#pragma unroll
      for (int it = 0; it < 2; ++it) {
        const int row = srow0 + it * 32;
        bf16x8 kb;
        kb[0] = (bf16)kreg[it][0].x; kb[1] = (bf16)kreg[it][0].y;
        kb[2] = (bf16)kreg[it][0].z; kb[3] = (bf16)kreg[it][0].w;
        kb[4] = (bf16)kreg[it][1].x; kb[5] = (bf16)kreg[it][1].y;
        kb[6] = (bf16)kreg[it][1].z; kb[7] = (bf16)kreg[it][1].w;
        *(bf16x8*)(Ks + row * LP + scol) = kb;
        *(bf16x8*)(Vs + row * LP + scol) = vreg[it];
      }
      __syncthreads();  // buf[j&1] ready; also orders j-2 reads vs these writes
      // issue next tile's global loads early (hide under compute)
      if (j < qt) {
        const int jn = j + 1;
#pragma unroll
        for (int it = 0; it < 2; ++it) {
          const int row = srow0 + it * 32;
          const float* kp = Kb + (size_t)(jn * 64 + row) * DH + scol;
          kreg[it][0] = *(const float4*)kp;
          kreg[it][1] = *(const float4*)(kp + 4);
          vreg[it] = *(const bf16x8*)(VTb + (size_t)row * SEQ + jn * 64 + scol);
        }
      }
      // scores S = Q K^T
      f32x4 s[4];
#pragma unroll
      for (int n = 0; n < 4; n++) s[n] = (f32x4){0.f, 0.f, 0.f, 0.f};
#pragma unroll
      for (int kk = 0; kk < 2; kk++) {
#pragma unroll
        for (int n = 0; n < 4; n++) {
          const int kr = n * 16 + ln;
          bf16x8 kf = *(const bf16x8*)(Ks + kr * LP + kk * 32 + hi * 8);
          s[n] = mfma16(qf[kk], kf, s[n]);
        }
      }
      const bool diag = (j == qt);
#pragma unroll
      for (int n = 0; n < 4; n++) {
#pragma unroll
        for (int reg = 0; reg < 4; reg++) {
          float v = s[n][reg] * (1.f / 64.f);  // scale by 1/d (not sqrt)
          if (diag) {
            const int col = j * 64 + n * 16 + ln;
            const int row = qrow_base + hi * 4 + reg;
            if (col > row) v = -1e10f;
          }
          s[n][reg] = v;
        }
      }
      // online softmax: row = 16 lanes sharing `hi`, 4 cols each
      float pm[4];
#pragma unroll
      for (int reg = 0; reg < 4; reg++)
        pm[reg] =
            fmaxf(fmaxf(s[0][reg], s[1][reg]), fmaxf(s[2][reg], s[3][reg]));
#pragma unroll
      for (int off = 1; off < 16; off <<= 1)
#pragma unroll
        for (int reg = 0; reg < 4; reg++)
          pm[reg] = fmaxf(pm[reg], __shfl_xor(pm[reg], off));
      float alpha[4];
#pragma unroll
      for (int reg = 0; reg < 4; reg++) {
        const float mnew = fmaxf(mrun[reg], pm[reg]);
        alpha[reg] = __expf(mrun[reg] - mnew);
        mrun[reg] = mnew;
      }
      float rs[4] = {0.f, 0.f, 0.f, 0.f};
#pragma unroll
      for (int n = 0; n < 4; n++)
#pragma unroll
        for (int reg = 0; reg < 4; reg++) {
          const float p = __expf(s[n][reg] - mrun[reg]);
          s[n][reg] = p;
          rs[reg] += p;
        }
#pragma unroll
      for (int off = 1; off < 16; off <<= 1)
#pragma unroll
        for (int reg = 0; reg < 4; reg++) rs[reg] += __shfl_xor(rs[reg], off);
#pragma unroll
      for (int reg = 0; reg < 4; reg++)
        lrun[reg] = lrun[reg] * alpha[reg] + rs[reg];
#pragma unroll
      for (int nd = 0; nd < 4; nd++)
#pragma unroll
        for (int reg = 0; reg < 4; reg++) o[nd][reg] *= alpha[reg];
      // P -> wave-private padded LDS (same-wave roundtrip, no barrier)
#pragma unroll
      for (int n = 0; n < 4; n++)
#pragma unroll
        for (int reg = 0; reg < 4; reg++)
          Psw[(hi * 4 + reg) * LP + n * 16 + ln] = (bf16)s[n][reg];
#pragma unroll
      for (int kk = 0; kk < 2; kk++) {
        bf16x8 pa = *(const bf16x8*)(Psw + ln * LP + kk * 32 + hi * 8);
#pragma unroll
        for (int nd = 0; nd < 4; nd++) {
          const int vr = nd * 16 + ln;
          bf16x8 vf = *(const bf16x8*)(Vs + vr * LP + kk * 32 + hi * 8);
          o[nd] = mfma16(pa, vf, o[nd]);
        }
      }
    }
    __syncthreads();  // half boundary: all reads done before next half's write
    // write merged-heads a (bf16): [B,S,NX]
#pragma unroll
    for (int nd = 0; nd < 4; nd++)
#pragma unroll
      for (int reg = 0; reg < 4; reg++) {
        const int srow = qrow_base + hi * 4 + reg;
        const float inv = 1.f / lrun[reg];
        Aout[((size_t)bq * SEQ + srow) * NXD + h * 64 + nd * 16 + ln] =
            (bf16)(o[nd][reg] * inv);
      }
  }
}

extern "C" void kernel_launch(void* const* d_in, const int* in_sizes, int n_in,
                              void* d_out, int out_size, void* d_ws,
                              size_t ws_size, hipStream_t stream) {
  const float* x = (const float*)d_in[0];        // [B,S,NX] fp32
  const float* w_attn = (const float*)d_in[1];   // [1024,3072] fp32
  const float* b_attn = (const float*)d_in[2];   // [3072] fp32
  const float* w_proj = (const float*)d_in[3];   // [1024,1024] fp32
  const float* b_proj = (const float*)d_in[4];   // [1024] fp32

  float* out = (float*)d_out;            // [B,S,NX] fp32
  float* kout = out + 4194304;           // present[0] [B,H,S,D] fp32
  float* vout = kout + 4194304;          // present[1] [B,H,S,D] fp32

  bf16* wT = (bf16*)d_ws;                // [3072][1024] bf16   6.29MB
  bf16* wpT = wT + 3072 * 1024;          // [1024][1024] bf16   2.10MB
  bf16* Qws = wpT + 1024 * 1024;         // [B,H,S,D]    bf16   8.39MB
  bf16* VTws = Qws + 4194304;            // [B,H,D,S]    bf16   8.39MB
  bf16* Aws = VTws + 4194304;            // [B,S,NX]     bf16   8.39MB (33.6MB)
  bf16* Xb = Aws;  // x-as-bf16 parks here until gemm<0> consumes it

  convert_f32_bf16<<<dim3(2048), 256, 0, stream>>>(x, Xb, 524288);
  transpose64_f2b<<<dim3(48, 16, 1), 256, 0, stream>>>(w_attn, wT, 1024, 3072);
  transpose64_f2b<<<dim3(16, 16, 1), 256, 0, stream>>>(w_proj, wpT, 1024,
                                                       1024);
  gemm128<0><<<dim3(24, 32), 256, 0, stream>>>(Xb, wT, b_attn, Qws, kout,
                                               vout);
  // V^T per head: fp32 [S][D] -> bf16 [D][S], batched over B*H=32
  transpose64_f2b<<<dim3(1, 32, 32), 256, 0, stream>>>(vout, VTws, 2048, 64);
  attn_kernel<<<dim3(NT / 2, 32), 256, 0, stream>>>(Qws, kout, VTws, Aws);
  gemm128<1><<<dim3(8, 32), 256, 0, stream>>>(Aws, wpT, b_proj, nullptr, out,
                                              nullptr);
}